// Round 3
// baseline (126.322 us; speedup 1.0000x reference)
//
#include <hip/hip_runtime.h>
#include <stdint.h>

// ONNX NonMaxSuppression: B=8, N=16384, C=80, MAX_OUT=50
// Fast kernel: one block per (b,c); single fused scan with fixed optimistic
// score cutoff compacts ~512 top candidates (keys+boxes) into LDS; wave 0
// then runs all 50 greedy rounds barrier-free with candidates in REGISTERS.
// Exactness: any block whose optimistic subset overflows CAP or exhausts
// while lower-scored candidates remain flags itself in d_ws; a gated slow
// kernel (the previously-verified adaptive 2-pass version) re-solves flagged
// lanes exactly. Flags rewritten every call (graph-replay deterministic).

#define NMS_B 8
#define NMS_N 16384
#define NMS_C 80
#define NMS_MAX_OUT 50
#define NTHREADS 256

// fast kernel
#define OPT_THR 0.96875f     // == bucket cut 240/256 over (0.5,1); E[cnt]=512, sigma~22
#define FCAP 768             // +11 sigma headroom
#define R_MAX 12             // ceil(FCAP/64)

// slow (fallback) kernel
#define NBUCK 256
#define SCAP 1024
#define T_MIN 320

typedef unsigned long long u64;
typedef unsigned int u32;

__device__ __forceinline__ float iou_exact(float4 A, float areaA, float4 Bx) {
    // bit-exact replica of the reference chain; returns 0 when inter==0
    float x1 = fmaxf(A.x, Bx.x);
    float y1 = fmaxf(A.y, Bx.y);
    float x2 = fminf(A.z, Bx.z);
    float y2 = fminf(A.w, Bx.w);
    float dx = fmaxf(__fsub_rn(x2, x1), 0.0f);
    float dy = fmaxf(__fsub_rn(y2, y1), 0.0f);
    if (!(dx > 0.0f && dy > 0.0f)) return 0.0f;   // inter==0 -> iou==0 exactly
    float inter = __fmul_rn(dx, dy);
    float areaB = __fmul_rn(__fsub_rn(Bx.z, Bx.x), __fsub_rn(Bx.w, Bx.y));
    float uni   = __fsub_rn(__fadd_rn(areaA, areaB), inter);
    return __fdiv_rn(inter, fmaxf(uni, 1e-9f));
}

template <bool OUT64>
__global__ __launch_bounds__(NTHREADS) void nms_fast(
    const float* __restrict__ boxes,
    const float* __restrict__ scores,
    const int* __restrict__ p_maxout,
    const float* __restrict__ p_iou,
    const float* __restrict__ p_sthr,
    void* __restrict__ out_raw,
    int* __restrict__ flags)
{
    __shared__ u64    skey[FCAP];
    __shared__ float4 sbox[FCAP];
    __shared__ int    s_cnt, s_total;

    const int tid = threadIdx.x;
    const int bc  = blockIdx.x;
    const int b   = bc / NMS_C;
    const int c   = bc % NMS_C;

    const float score_thr = p_sthr[0];
    const float iou_thr   = p_iou[0];
    int maxo = p_maxout[0];
    if (maxo > NMS_MAX_OUT) maxo = NMS_MAX_OUT;
    if (maxo < 0) maxo = 0;

    int*       out32 = (int*)out_raw       + (size_t)bc * NMS_MAX_OUT * 3;
    long long* out64 = (long long*)out_raw + (size_t)bc * NMS_MAX_OUT * 3;
    for (int i = tid; i < NMS_MAX_OUT * 3; i += NTHREADS) {
        if (OUT64) out64[i] = -1LL; else out32[i] = -1;
    }

    if (tid == 0) { s_cnt = 0; s_total = 0; }
    __syncthreads();

    const float4* sc4     = (const float4*)(scores + ((size_t)b * NMS_C + c) * NMS_N);
    const float4* boxes_b = (const float4*)(boxes + (size_t)b * NMS_N * 4);

    // ---- single fused scan: count all candidates, compact optimistic subset ----
    int local_total = 0;
    for (int i = tid; i < NMS_N / 4; i += NTHREADS) {
        float4 s4 = sc4[i];
        float ss[4] = {s4.x, s4.y, s4.z, s4.w};
        #pragma unroll
        for (int j = 0; j < 4; ++j) {
            float s = ss[j];
            if (s > score_thr) {
                ++local_total;
                if (s >= OPT_THR) {
                    int n = i * 4 + j;
                    int p = atomicAdd(&s_cnt, 1);
                    if (p < FCAP) {
                        skey[p] = ((u64)__float_as_uint(s) << 24)
                                | ((u64)(NMS_N - 1 - n) << 10)
                                | (u64)p;
                        sbox[p] = boxes_b[n];
                    }
                }
            }
        }
    }
    atomicAdd(&s_total, local_total);
    __syncthreads();

    const int  m        = (s_cnt < FCAP) ? s_cnt : FCAP;
    const bool overflow = (s_cnt > FCAP);
    const int  rem      = s_total - s_cnt;   // candidates below the optimistic cut

    if (overflow) {                          // uniform: whole block bails to slow path
        if (tid == 0) flags[bc] = 1;
        return;
    }
    if (tid >= 64) return;                   // waves 1..3 retire; wave 0 runs rounds
    const int lane = tid;

    // ---- pull candidates into registers (statically indexed) ----
    u64    k[R_MAX];
    float4 bx[R_MAX];
    #pragma unroll
    for (int j = 0; j < R_MAX; ++j) {
        int idx = j * 64 + lane;
        k[j]  = (idx < m) ? skey[idx] : 0ull;
        bx[j] = sbox[idx < FCAP ? idx : 0];  // dead entries never used
    }

    // ---- barrier-free greedy rounds (wave-synchronous) ----
    int need_slow = 0;
    for (int t = 0; t < maxo; ++t) {
        u64 lmax = 0ull;
        #pragma unroll
        for (int j = 0; j < R_MAX; ++j) if (k[j] > lmax) lmax = k[j];
        #pragma unroll
        for (int s = 32; s > 0; s >>= 1) {
            u64 o = __shfl_xor(lmax, s, 64);
            if (o > lmax) lmax = o;
        }
        if (lmax == 0ull) {                  // subset exhausted
            if (rem > 0) need_slow = 1;      // lower-scored candidates remain
            break;
        }
        const int slot = (int)(lmax & 0x3FFull);
        const int n    = NMS_N - 1 - (int)((lmax >> 10) & 0x3FFFull);
        if (lane == 0) {
            if (OUT64) {
                out64[t * 3 + 0] = (long long)b;
                out64[t * 3 + 1] = (long long)c;
                out64[t * 3 + 2] = (long long)n;
            } else {
                out32[t * 3 + 0] = b;
                out32[t * 3 + 1] = c;
                out32[t * 3 + 2] = n;
            }
        }
        const float4 A = sbox[slot];         // uniform LDS read -> broadcast
        const int jb = slot >> 6, lb = slot & 63;
        #pragma unroll
        for (int j = 0; j < R_MAX; ++j)      // explicit self-kill (zero-area safe)
            if (j == jb && lane == lb) k[j] = 0ull;
        const float areaA = __fmul_rn(__fsub_rn(A.z, A.x), __fsub_rn(A.w, A.y));
        #pragma unroll
        for (int j = 0; j < R_MAX; ++j) {
            if (k[j]) {
                if (iou_exact(A, areaA, bx[j]) > iou_thr) k[j] = 0ull;
            }
        }
    }
    if (lane == 0) flags[bc] = need_slow;
}

// ---- slow exact fallback: the previously-verified adaptive 2-pass kernel ----
__device__ __forceinline__ int bucketf(float s) {
    int v = (int)__float_as_uint(s) - 0x3F000000;
    v >>= 15;
    return v < 0 ? 0 : (v > 255 ? 255 : v);
}

template <bool OUT64>
__global__ __launch_bounds__(NTHREADS) void nms_slow(
    const float* __restrict__ boxes,
    const float* __restrict__ scores,
    const int* __restrict__ p_maxout,
    const float* __restrict__ p_iou,
    const float* __restrict__ p_sthr,
    void* __restrict__ out_raw,
    const int* __restrict__ flags)
{
    __shared__ int    hist[NBUCK];
    __shared__ u64    key[SCAP];
    __shared__ float4 cbox[SCAP];
    __shared__ float4 selbox[NMS_MAX_OUT];
    __shared__ u64    s_wmax[NTHREADS / 64];
    __shared__ u64    s_best;
    __shared__ int    s_cnt, s_cutLo, s_cutHi, s_rem, s_state;

    const int tid = threadIdx.x;
    const int bc  = blockIdx.x;
    if (flags && flags[bc] == 0) return;     // uniform exit, before any barrier
    const int b   = bc / NMS_C;
    const int c   = bc % NMS_C;

    const float score_thr = p_sthr[0];
    const float iou_thr   = p_iou[0];
    int maxo = p_maxout[0];
    if (maxo > NMS_MAX_OUT) maxo = NMS_MAX_OUT;
    if (maxo < 0) maxo = 0;

    int*       out32 = (int*)out_raw       + (size_t)bc * NMS_MAX_OUT * 3;
    long long* out64 = (long long*)out_raw + (size_t)bc * NMS_MAX_OUT * 3;
    for (int i = tid; i < NMS_MAX_OUT * 3; i += NTHREADS) {
        if (OUT64) out64[i] = -1LL; else out32[i] = -1;
    }

    const float*  sc      = scores + ((size_t)b * NMS_C + c) * NMS_N;
    const float4* sc4     = (const float4*)sc;
    const float4* boxes_b = (const float4*)(boxes + (size_t)b * NMS_N * 4);

    for (int i = tid; i < NBUCK; i += NTHREADS) hist[i] = 0;
    if (tid == 0) s_cnt = 0;
    __syncthreads();
    for (int i = tid; i < NMS_N / 4; i += NTHREADS) {
        float4 s4 = sc4[i];
        float ss[4] = {s4.x, s4.y, s4.z, s4.w};
        #pragma unroll
        for (int j = 0; j < 4; ++j)
            if (ss[j] > score_thr) atomicAdd(&hist[bucketf(ss[j])], 1);
    }
    __syncthreads();

    if (tid == 0) {
        int cum = 0, cut = NBUCK;
        for (int bk = NBUCK - 1; bk >= 0; --bk) {
            int h = hist[bk];
            if (cum > 0 && cum + h > SCAP) break;
            cum += h; cut = bk;
            if (cum >= T_MIN) break;
        }
        s_cutLo = cut; s_cutHi = NBUCK - 1;
        int rem = 0;
        for (int bk = 0; bk < cut; ++bk) rem += hist[bk];
        s_rem = rem;
    }
    __syncthreads();

    auto compact = [&](int lo, int hi) {
        for (int i = tid; i < NMS_N / 4; i += NTHREADS) {
            float4 s4 = sc4[i];
            float ss[4] = {s4.x, s4.y, s4.z, s4.w};
            #pragma unroll
            for (int j = 0; j < 4; ++j) {
                float s = ss[j];
                if (s > score_thr) {
                    int bk = bucketf(s);
                    if (bk >= lo && bk <= hi) {
                        int n = i * 4 + j;
                        int p = atomicAdd(&s_cnt, 1);
                        if (p < SCAP) {
                            key[p] = ((u64)__float_as_uint(s) << 24)
                                   | ((u64)(NMS_N - 1 - n) << 10)
                                   | (u64)p;
                            cbox[p] = boxes_b[n];
                        }
                    }
                }
            }
        }
    };
    compact(s_cutLo, s_cutHi);
    __syncthreads();

    int t = 0;
    while (t < maxo) {
        int m = s_cnt; if (m > SCAP) m = SCAP;
        u64 lmax = 0ull;
        for (int i = tid; i < m; i += NTHREADS) {
            u64 k = key[i];
            if (k > lmax) lmax = k;
        }
        #pragma unroll
        for (int off = 32; off > 0; off >>= 1) {
            u64 o = __shfl_down(lmax, off);
            if (o > lmax) lmax = o;
        }
        if ((tid & 63) == 0) s_wmax[tid >> 6] = lmax;
        __syncthreads();
        if (tid == 0) {
            u64 best = s_wmax[0];
            #pragma unroll
            for (int w = 1; w < NTHREADS / 64; ++w)
                if (s_wmax[w] > best) best = s_wmax[w];
            s_best = best;
            if (best) {
                int slot = (int)(best & 0x3FFull);
                int n    = NMS_N - 1 - (int)((best >> 10) & 0x3FFFull);
                key[slot] = 0ull;
                if (OUT64) {
                    out64[t * 3 + 0] = (long long)b;
                    out64[t * 3 + 1] = (long long)c;
                    out64[t * 3 + 2] = (long long)n;
                } else {
                    out32[t * 3 + 0] = b;
                    out32[t * 3 + 1] = c;
                    out32[t * 3 + 2] = n;
                }
                selbox[t] = cbox[slot];
                s_state = 0;
            } else if (s_rem == 0) {
                s_state = 2;
            } else {
                int hiB = s_cutLo - 1;
                int cum = 0, cut = hiB + 1;
                for (int bk = hiB; bk >= 0; --bk) {
                    int h = hist[bk];
                    if (cum > 0 && cum + h > SCAP) break;
                    cum += h; cut = bk;
                    if (cum >= T_MIN) break;
                }
                s_cutLo = cut; s_cutHi = hiB;
                int rem = 0;
                for (int bk = 0; bk < cut; ++bk) rem += hist[bk];
                s_rem = rem;
                s_cnt = 0;
                s_state = 1;
            }
        }
        __syncthreads();

        if (s_state == 2) break;

        if (s_state == 0) {
            const float4 A = selbox[t];
            const float areaA = __fmul_rn(__fsub_rn(A.z, A.x), __fsub_rn(A.w, A.y));
            int m0 = s_cnt; if (m0 > SCAP) m0 = SCAP;
            for (int i = tid; i < m0; i += NTHREADS) {
                u64 k = key[i];
                if (!k) continue;
                if (iou_exact(A, areaA, cbox[i]) > iou_thr) key[i] = 0ull;
            }
            __syncthreads();
            ++t;
        } else {
            compact(s_cutLo, s_cutHi);
            __syncthreads();
            int m2 = s_cnt; if (m2 > SCAP) m2 = SCAP;
            for (int i = tid; i < m2; i += NTHREADS) {
                u64 k = key[i];
                if (!k) continue;
                float4 Bx = cbox[i];
                for (int j = 0; j < t; ++j) {
                    float4 A = selbox[j];
                    float areaA = __fmul_rn(__fsub_rn(A.z, A.x), __fsub_rn(A.w, A.y));
                    if (iou_exact(A, areaA, Bx) > iou_thr) { key[i] = 0ull; break; }
                }
            }
            __syncthreads();
        }
    }
}

extern "C" void kernel_launch(void* const* d_in, const int* in_sizes, int n_in,
                              void* d_out, int out_size, void* d_ws, size_t ws_size,
                              hipStream_t stream) {
    const float* boxes  = (const float*)d_in[0];
    const float* scores = (const float*)d_in[1];
    const int*   p_maxo = (const int*)d_in[2];
    const float* p_iou  = (const float*)d_in[3];
    const float* p_sthr = (const float*)d_in[4];

    const dim3 grid(NMS_B * NMS_C);
    const dim3 block(NTHREADS);
    const bool out64 = (out_size == NMS_B * NMS_C * NMS_MAX_OUT * 3 * 2);

    int* flags = (ws_size >= (size_t)NMS_B * NMS_C * sizeof(int)) ? (int*)d_ws : nullptr;

    if (out64) {
        if (flags)
            hipLaunchKernelGGL(nms_fast<true>, grid, block, 0, stream,
                               boxes, scores, p_maxo, p_iou, p_sthr, d_out, flags);
        hipLaunchKernelGGL(nms_slow<true>, grid, block, 0, stream,
                           boxes, scores, p_maxo, p_iou, p_sthr, d_out, flags);
    } else {
        if (flags)
            hipLaunchKernelGGL(nms_fast<false>, grid, block, 0, stream,
                               boxes, scores, p_maxo, p_iou, p_sthr, d_out, flags);
        hipLaunchKernelGGL(nms_slow<false>, grid, block, 0, stream,
                           boxes, scores, p_maxo, p_iou, p_sthr, d_out, flags);
    }
}

// Round 4
// 105.589 us; speedup vs baseline: 1.1964x; 1.1964x over previous
//
#include <hip/hip_runtime.h>
#include <stdint.h>

// ONNX NonMaxSuppression: B=8, N=16384, C=80, MAX_OUT=50
// nms_fast: one block per (b,c).
//   phase A: streaming score scan (4x unrolled), push keys+indices of
//            candidates above a fixed optimistic cutoff into LDS
//   phase B: cooperative box gather into LDS **SoA** (conflict-free reads)
//   tail:    wave 0 runs 50 greedy rounds wave-synchronously; keys in
//            registers (k[8] = 16 VGPRs, no spill), boxes from LDS SoA.
// Exactness: overflow or exhaustion-with-remainder flags the lane in d_ws;
// gated nms_slow (previously-verified adaptive 2-pass kernel) re-solves it.

#define NMS_B 8
#define NMS_N 16384
#define NMS_C 80
#define NMS_MAX_OUT 50
#define NTHREADS 256

// fast kernel
#define OPT_THR 0.9765625f   // bits 0x3F7A0000; E[cnt]=384, sigma~19
#define FCAP 512             // overflow = +6.6 sigma
#define R_MAX 8              // FCAP/64

// slow (fallback) kernel
#define NBUCK 256
#define SCAP 1024
#define T_MIN 320

typedef unsigned long long u64;
typedef unsigned int u32;

__device__ __forceinline__ float iou_exact(float4 A, float areaA, float4 Bx) {
    float x1 = fmaxf(A.x, Bx.x);
    float y1 = fmaxf(A.y, Bx.y);
    float x2 = fminf(A.z, Bx.z);
    float y2 = fminf(A.w, Bx.w);
    float dx = fmaxf(__fsub_rn(x2, x1), 0.0f);
    float dy = fmaxf(__fsub_rn(y2, y1), 0.0f);
    if (!(dx > 0.0f && dy > 0.0f)) return 0.0f;   // inter==0 -> iou==0 exactly
    float inter = __fmul_rn(dx, dy);
    float areaB = __fmul_rn(__fsub_rn(Bx.z, Bx.x), __fsub_rn(Bx.w, Bx.y));
    float uni   = __fsub_rn(__fadd_rn(areaA, areaB), inter);
    return __fdiv_rn(inter, fmaxf(uni, 1e-9f));
}

template <bool OUT64>
__global__ __launch_bounds__(NTHREADS) void nms_fast(
    const float* __restrict__ boxes,
    const float* __restrict__ scores,
    const int* __restrict__ p_maxout,
    const float* __restrict__ p_iou,
    const float* __restrict__ p_sthr,
    void* __restrict__ out_raw,
    int* __restrict__ flags)
{
    __shared__ u64   skey[FCAP];
    __shared__ int   sn[FCAP];
    __shared__ float sx[FCAP], sy[FCAP], sz[FCAP], sw[FCAP];
    __shared__ int   s_cnt, s_total;

    const int tid = threadIdx.x;
    const int bc  = blockIdx.x;
    const int b   = bc / NMS_C;
    const int c   = bc % NMS_C;

    const float score_thr = p_sthr[0];
    const float iou_thr   = p_iou[0];
    int maxo = p_maxout[0];
    if (maxo > NMS_MAX_OUT) maxo = NMS_MAX_OUT;
    if (maxo < 0) maxo = 0;

    int*       out32 = (int*)out_raw       + (size_t)bc * NMS_MAX_OUT * 3;
    long long* out64 = (long long*)out_raw + (size_t)bc * NMS_MAX_OUT * 3;
    for (int i = tid; i < NMS_MAX_OUT * 3; i += NTHREADS) {
        if (OUT64) out64[i] = -1LL; else out32[i] = -1;
    }

    if (tid == 0) { s_cnt = 0; s_total = 0; }
    __syncthreads();

    const float4* sc4     = (const float4*)(scores + ((size_t)b * NMS_C + c) * NMS_N);
    const float4* boxes_b = (const float4*)(boxes + (size_t)b * NMS_N * 4);

    // ---- phase A: streaming score scan (scores only; no dependent gathers) ----
    int local_total = 0;
    #pragma unroll 1
    for (int it = 0; it < (NMS_N / 4) / NTHREADS; it += 4) {
        // 4 independent loads in flight
        float4 a0 = sc4[(it + 0) * NTHREADS + tid];
        float4 a1 = sc4[(it + 1) * NTHREADS + tid];
        float4 a2 = sc4[(it + 2) * NTHREADS + tid];
        float4 a3 = sc4[(it + 3) * NTHREADS + tid];
        float4 av[4] = {a0, a1, a2, a3};
        #pragma unroll
        for (int u = 0; u < 4; ++u) {
            const int i = (it + u) * NTHREADS + tid;
            float ss[4] = {av[u].x, av[u].y, av[u].z, av[u].w};
            #pragma unroll
            for (int j = 0; j < 4; ++j) {
                float s = ss[j];
                local_total += (s > score_thr) ? 1 : 0;   // predicated, no branch
                if (s >= OPT_THR) {                       // rare (~1.6%)
                    int n = i * 4 + j;
                    int p = atomicAdd(&s_cnt, 1);
                    if (p < FCAP) {
                        skey[p] = ((u64)__float_as_uint(s) << 23)
                                | ((u64)(NMS_N - 1 - n) << 9)
                                | (u64)p;
                        sn[p] = n;
                    }
                }
            }
        }
    }
    atomicAdd(&s_total, local_total);
    __syncthreads();

    const int  m        = (s_cnt < FCAP) ? s_cnt : FCAP;
    const bool overflow = (s_cnt > FCAP);
    const int  rem      = s_total - s_cnt;      // candidates below optimistic cut

    if (overflow) {                             // uniform block-wide bail
        if (tid == 0) flags[bc] = 1;
        return;
    }

    // ---- phase B: cooperative box gather into SoA LDS ----
    for (int i = tid; i < m; i += NTHREADS) {
        float4 bb = boxes_b[sn[i]];
        sx[i] = bb.x; sy[i] = bb.y; sz[i] = bb.z; sw[i] = bb.w;
    }
    __syncthreads();

    if (tid >= 64) return;                      // waves 1..3 retire
    const int lane = tid;

    // keys in registers (16 VGPRs), statically indexed
    u64 k[R_MAX];
    #pragma unroll
    for (int j = 0; j < R_MAX; ++j) {
        int idx = j * 64 + lane;
        k[j] = (idx < m) ? skey[idx] : 0ull;
    }

    // ---- barrier-free greedy rounds (wave-synchronous) ----
    int need_slow = 0;
    for (int t = 0; t < maxo; ++t) {
        u64 lmax = 0ull;
        #pragma unroll
        for (int j = 0; j < R_MAX; ++j) if (k[j] > lmax) lmax = k[j];
        #pragma unroll
        for (int s = 32; s > 0; s >>= 1) {
            u64 o = __shfl_xor(lmax, s, 64);
            if (o > lmax) lmax = o;
        }
        if (lmax == 0ull) {
            if (rem > 0) need_slow = 1;
            break;
        }
        const int slot = (int)(lmax & 0x1FFull);
        const int n    = NMS_N - 1 - (int)((lmax >> 9) & 0x3FFFull);
        if (lane == 0) {
            if (OUT64) {
                out64[t * 3 + 0] = (long long)b;
                out64[t * 3 + 1] = (long long)c;
                out64[t * 3 + 2] = (long long)n;
            } else {
                out32[t * 3 + 0] = b;
                out32[t * 3 + 1] = c;
                out32[t * 3 + 2] = n;
            }
        }
        // selected box: uniform LDS reads -> broadcast
        const float4 A = make_float4(sx[slot], sy[slot], sz[slot], sw[slot]);
        const int jb = slot >> 6, lb = slot & 63;
        #pragma unroll
        for (int j = 0; j < R_MAX; ++j)         // explicit self-kill
            if (j == jb && lane == lb) k[j] = 0ull;
        const float areaA = __fmul_rn(__fsub_rn(A.z, A.x), __fsub_rn(A.w, A.y));
        #pragma unroll
        for (int j = 0; j < R_MAX; ++j) {
            if (k[j]) {
                const int idx = j * 64 + lane;  // conflict-free SoA reads
                float4 Bx = make_float4(sx[idx], sy[idx], sz[idx], sw[idx]);
                if (iou_exact(A, areaA, Bx) > iou_thr) k[j] = 0ull;
            }
        }
    }
    if (lane == 0) flags[bc] = need_slow;
}

// ---- slow exact fallback (verified round-2 structure, flag-gated) ----
__device__ __forceinline__ int bucketf(float s) {
    int v = (int)__float_as_uint(s) - 0x3F000000;
    v >>= 15;
    return v < 0 ? 0 : (v > 255 ? 255 : v);
}

template <bool OUT64>
__global__ __launch_bounds__(NTHREADS) void nms_slow(
    const float* __restrict__ boxes,
    const float* __restrict__ scores,
    const int* __restrict__ p_maxout,
    const float* __restrict__ p_iou,
    const float* __restrict__ p_sthr,
    void* __restrict__ out_raw,
    const int* __restrict__ flags)
{
    __shared__ int    hist[NBUCK];
    __shared__ u64    key[SCAP];
    __shared__ float4 cbox[SCAP];
    __shared__ float4 selbox[NMS_MAX_OUT];
    __shared__ u64    s_wmax[NTHREADS / 64];
    __shared__ u64    s_best;
    __shared__ int    s_cnt, s_cutLo, s_cutHi, s_rem, s_state;

    const int tid = threadIdx.x;
    const int bc  = blockIdx.x;
    if (flags && flags[bc] == 0) return;     // uniform exit before any barrier
    const int b   = bc / NMS_C;
    const int c   = bc % NMS_C;

    const float score_thr = p_sthr[0];
    const float iou_thr   = p_iou[0];
    int maxo = p_maxout[0];
    if (maxo > NMS_MAX_OUT) maxo = NMS_MAX_OUT;
    if (maxo < 0) maxo = 0;

    int*       out32 = (int*)out_raw       + (size_t)bc * NMS_MAX_OUT * 3;
    long long* out64 = (long long*)out_raw + (size_t)bc * NMS_MAX_OUT * 3;
    for (int i = tid; i < NMS_MAX_OUT * 3; i += NTHREADS) {
        if (OUT64) out64[i] = -1LL; else out32[i] = -1;
    }

    const float*  sc      = scores + ((size_t)b * NMS_C + c) * NMS_N;
    const float4* sc4     = (const float4*)sc;
    const float4* boxes_b = (const float4*)(boxes + (size_t)b * NMS_N * 4);

    for (int i = tid; i < NBUCK; i += NTHREADS) hist[i] = 0;
    if (tid == 0) s_cnt = 0;
    __syncthreads();
    for (int i = tid; i < NMS_N / 4; i += NTHREADS) {
        float4 s4 = sc4[i];
        float ss[4] = {s4.x, s4.y, s4.z, s4.w};
        #pragma unroll
        for (int j = 0; j < 4; ++j)
            if (ss[j] > score_thr) atomicAdd(&hist[bucketf(ss[j])], 1);
    }
    __syncthreads();

    if (tid == 0) {
        int cum = 0, cut = NBUCK;
        for (int bk = NBUCK - 1; bk >= 0; --bk) {
            int h = hist[bk];
            if (cum > 0 && cum + h > SCAP) break;
            cum += h; cut = bk;
            if (cum >= T_MIN) break;
        }
        s_cutLo = cut; s_cutHi = NBUCK - 1;
        int rem = 0;
        for (int bk = 0; bk < cut; ++bk) rem += hist[bk];
        s_rem = rem;
    }
    __syncthreads();

    auto compact = [&](int lo, int hi) {
        for (int i = tid; i < NMS_N / 4; i += NTHREADS) {
            float4 s4 = sc4[i];
            float ss[4] = {s4.x, s4.y, s4.z, s4.w};
            #pragma unroll
            for (int j = 0; j < 4; ++j) {
                float s = ss[j];
                if (s > score_thr) {
                    int bk = bucketf(s);
                    if (bk >= lo && bk <= hi) {
                        int n = i * 4 + j;
                        int p = atomicAdd(&s_cnt, 1);
                        if (p < SCAP) {
                            key[p] = ((u64)__float_as_uint(s) << 24)
                                   | ((u64)(NMS_N - 1 - n) << 10)
                                   | (u64)p;
                            cbox[p] = boxes_b[n];
                        }
                    }
                }
            }
        }
    };
    compact(s_cutLo, s_cutHi);
    __syncthreads();

    int t = 0;
    while (t < maxo) {
        int m = s_cnt; if (m > SCAP) m = SCAP;
        u64 lmax = 0ull;
        for (int i = tid; i < m; i += NTHREADS) {
            u64 k = key[i];
            if (k > lmax) lmax = k;
        }
        #pragma unroll
        for (int off = 32; off > 0; off >>= 1) {
            u64 o = __shfl_down(lmax, off);
            if (o > lmax) lmax = o;
        }
        if ((tid & 63) == 0) s_wmax[tid >> 6] = lmax;
        __syncthreads();
        if (tid == 0) {
            u64 best = s_wmax[0];
            #pragma unroll
            for (int w = 1; w < NTHREADS / 64; ++w)
                if (s_wmax[w] > best) best = s_wmax[w];
            s_best = best;
            if (best) {
                int slot = (int)(best & 0x3FFull);
                int n    = NMS_N - 1 - (int)((best >> 10) & 0x3FFFull);
                key[slot] = 0ull;
                if (OUT64) {
                    out64[t * 3 + 0] = (long long)b;
                    out64[t * 3 + 1] = (long long)c;
                    out64[t * 3 + 2] = (long long)n;
                } else {
                    out32[t * 3 + 0] = b;
                    out32[t * 3 + 1] = c;
                    out32[t * 3 + 2] = n;
                }
                selbox[t] = cbox[slot];
                s_state = 0;
            } else if (s_rem == 0) {
                s_state = 2;
            } else {
                int hiB = s_cutLo - 1;
                int cum = 0, cut = hiB + 1;
                for (int bk = hiB; bk >= 0; --bk) {
                    int h = hist[bk];
                    if (cum > 0 && cum + h > SCAP) break;
                    cum += h; cut = bk;
                    if (cum >= T_MIN) break;
                }
                s_cutLo = cut; s_cutHi = hiB;
                int rem = 0;
                for (int bk = 0; bk < cut; ++bk) rem += hist[bk];
                s_rem = rem;
                s_cnt = 0;
                s_state = 1;
            }
        }
        __syncthreads();

        if (s_state == 2) break;

        if (s_state == 0) {
            const float4 A = selbox[t];
            const float areaA = __fmul_rn(__fsub_rn(A.z, A.x), __fsub_rn(A.w, A.y));
            int m0 = s_cnt; if (m0 > SCAP) m0 = SCAP;
            for (int i = tid; i < m0; i += NTHREADS) {
                u64 k = key[i];
                if (!k) continue;
                if (iou_exact(A, areaA, cbox[i]) > iou_thr) key[i] = 0ull;
            }
            __syncthreads();
            ++t;
        } else {
            compact(s_cutLo, s_cutHi);
            __syncthreads();
            int m2 = s_cnt; if (m2 > SCAP) m2 = SCAP;
            for (int i = tid; i < m2; i += NTHREADS) {
                u64 k = key[i];
                if (!k) continue;
                float4 Bx = cbox[i];
                for (int j = 0; j < t; ++j) {
                    float4 A = selbox[j];
                    float areaA = __fmul_rn(__fsub_rn(A.z, A.x), __fsub_rn(A.w, A.y));
                    if (iou_exact(A, areaA, Bx) > iou_thr) { key[i] = 0ull; break; }
                }
            }
            __syncthreads();
        }
    }
}

extern "C" void kernel_launch(void* const* d_in, const int* in_sizes, int n_in,
                              void* d_out, int out_size, void* d_ws, size_t ws_size,
                              hipStream_t stream) {
    const float* boxes  = (const float*)d_in[0];
    const float* scores = (const float*)d_in[1];
    const int*   p_maxo = (const int*)d_in[2];
    const float* p_iou  = (const float*)d_in[3];
    const float* p_sthr = (const float*)d_in[4];

    const dim3 grid(NMS_B * NMS_C);
    const dim3 block(NTHREADS);
    const bool out64 = (out_size == NMS_B * NMS_C * NMS_MAX_OUT * 3 * 2);

    int* flags = (ws_size >= (size_t)NMS_B * NMS_C * sizeof(int)) ? (int*)d_ws : nullptr;

    if (out64) {
        if (flags)
            hipLaunchKernelGGL(nms_fast<true>, grid, block, 0, stream,
                               boxes, scores, p_maxo, p_iou, p_sthr, d_out, flags);
        hipLaunchKernelGGL(nms_slow<true>, grid, block, 0, stream,
                           boxes, scores, p_maxo, p_iou, p_sthr, d_out, flags);
    } else {
        if (flags)
            hipLaunchKernelGGL(nms_fast<false>, grid, block, 0, stream,
                               boxes, scores, p_maxo, p_iou, p_sthr, d_out, flags);
        hipLaunchKernelGGL(nms_slow<false>, grid, block, 0, stream,
                           boxes, scores, p_maxo, p_iou, p_sthr, d_out, flags);
    }
}

// Round 5
// 96.174 us; speedup vs baseline: 1.3135x; 1.0979x over previous
//
#include <hip/hip_runtime.h>
#include <stdint.h>

// ONNX NonMaxSuppression: B=8, N=16384, C=80, MAX_OUT=50
// nms_fast, one block per (b,c):
//   phase A: streaming score scan; push keys (score_bits<<32 | invidx<<18)
//            of candidates above fixed optimistic cutoff into LDS
//   phase B: bitonic sort (desc) of 512-padded keys, 4 waves, 45 stages
//   phase C: gather candidate boxes by rank into LDS SoA
//   phase D: wave-0 sorted walk: alive bitmask 1 u64/lane; per selection,
//            live suppression row via __ballot of bit-exact IoU per lane.
//            Sorted-order walk + alive mask == greedy argmax NMS exactly.
// Exactness: overflow or exhaustion-with-remainder flags the lane in d_ws;
// gated nms_slow (verified adaptive 2-pass kernel) re-solves those lanes.

#define NMS_B 8
#define NMS_N 16384
#define NMS_C 80
#define NMS_MAX_OUT 50
#define NTHREADS 256

// fast kernel
#define OPT_THR 0.9765625f   // E[cnt]=384, sigma~19.4; FCAP=512 -> +6.6 sigma
#define FCAP 512
#define WMAX (FCAP / 64)     // 8 alive words

// slow (fallback) kernel
#define NBUCK 256
#define SCAP 1024
#define T_MIN 320

typedef unsigned long long u64;
typedef unsigned int u32;

__device__ __forceinline__ float iou_exact(float4 A, float areaA, float4 Bx) {
    float x1 = fmaxf(A.x, Bx.x);
    float y1 = fmaxf(A.y, Bx.y);
    float x2 = fminf(A.z, Bx.z);
    float y2 = fminf(A.w, Bx.w);
    float dx = fmaxf(__fsub_rn(x2, x1), 0.0f);
    float dy = fmaxf(__fsub_rn(y2, y1), 0.0f);
    if (!(dx > 0.0f && dy > 0.0f)) return 0.0f;   // inter==0 -> iou==0 exactly
    float inter = __fmul_rn(dx, dy);
    float areaB = __fmul_rn(__fsub_rn(Bx.z, Bx.x), __fsub_rn(Bx.w, Bx.y));
    float uni   = __fsub_rn(__fadd_rn(areaA, areaB), inter);
    return __fdiv_rn(inter, fmaxf(uni, 1e-9f));
}

template <bool OUT64>
__global__ __launch_bounds__(NTHREADS) void nms_fast(
    const float* __restrict__ boxes,
    const float* __restrict__ scores,
    const int* __restrict__ p_maxout,
    const float* __restrict__ p_iou,
    const float* __restrict__ p_sthr,
    void* __restrict__ out_raw,
    int* __restrict__ flags)
{
    __shared__ u64   skey[FCAP];
    __shared__ float sx[FCAP], sy[FCAP], sz[FCAP], sw[FCAP];
    __shared__ int   s_cnt, s_total;

    const int tid = threadIdx.x;
    const int bc  = blockIdx.x;
    const int b   = bc / NMS_C;
    const int c   = bc % NMS_C;

    const float score_thr = p_sthr[0];
    const float iou_thr   = p_iou[0];
    int maxo = p_maxout[0];
    if (maxo > NMS_MAX_OUT) maxo = NMS_MAX_OUT;
    if (maxo < 0) maxo = 0;

    int*       out32 = (int*)out_raw       + (size_t)bc * NMS_MAX_OUT * 3;
    long long* out64 = (long long*)out_raw + (size_t)bc * NMS_MAX_OUT * 3;
    for (int i = tid; i < NMS_MAX_OUT * 3; i += NTHREADS) {
        if (OUT64) out64[i] = -1LL; else out32[i] = -1;
    }

    // pad keys, init counters
    skey[tid] = 0ull;
    skey[tid + 256] = 0ull;
    if (tid == 0) { s_cnt = 0; s_total = 0; }
    __syncthreads();

    const float4* sc4     = (const float4*)(scores + ((size_t)b * NMS_C + c) * NMS_N);
    const float4* boxes_b = (const float4*)(boxes + (size_t)b * NMS_N * 4);

    // ---- phase A: streaming score scan ----
    int local_total = 0;
    #pragma unroll 1
    for (int it = 0; it < (NMS_N / 4) / NTHREADS; it += 4) {
        float4 a0 = sc4[(it + 0) * NTHREADS + tid];
        float4 a1 = sc4[(it + 1) * NTHREADS + tid];
        float4 a2 = sc4[(it + 2) * NTHREADS + tid];
        float4 a3 = sc4[(it + 3) * NTHREADS + tid];
        float4 av[4] = {a0, a1, a2, a3};
        #pragma unroll
        for (int u = 0; u < 4; ++u) {
            const int i = (it + u) * NTHREADS + tid;
            float ss[4] = {av[u].x, av[u].y, av[u].z, av[u].w};
            #pragma unroll
            for (int j = 0; j < 4; ++j) {
                float s = ss[j];
                bool cand = (s > score_thr);
                local_total += cand ? 1 : 0;
                if (cand && s >= OPT_THR) {          // rare (~2.3%)
                    int n = i * 4 + j;
                    int p = atomicAdd(&s_cnt, 1);
                    if (p < FCAP) {
                        skey[p] = ((u64)__float_as_uint(s) << 32)
                                | ((u64)(NMS_N - 1 - n) << 18);
                    }
                }
            }
        }
    }
    atomicAdd(&s_total, local_total);
    __syncthreads();

    const int  m        = (s_cnt < FCAP) ? s_cnt : FCAP;
    const bool overflow = (s_cnt > FCAP);
    const int  rem      = s_total - s_cnt;   // candidates below optimistic cut

    if (overflow) {                          // uniform block-wide bail
        if (tid == 0) flags[bc] = 1;
        return;
    }

    // ---- phase B: bitonic sort descending over FCAP=512 keys ----
    // 45 stages, 256 threads = 1 compare-exchange each, barrier per stage.
    for (int kk = 2; kk <= FCAP; kk <<= 1) {
        for (int jj = kk >> 1; jj > 0; jj >>= 1) {
            int i  = 2 * jj * (tid / jj) + (tid % jj);
            int p2 = i + jj;
            bool dirDesc = ((i & kk) == 0);
            u64 a = skey[i], bkey = skey[p2];
            bool swap = dirDesc ? (a < bkey) : (a > bkey);
            if (swap) { skey[i] = bkey; skey[p2] = a; }
            __syncthreads();
        }
    }

    // ---- phase C: gather boxes by rank into SoA LDS ----
    #pragma unroll
    for (int r = tid; r < FCAP; r += NTHREADS) {
        u64 kk = skey[r];
        int n = NMS_N - 1 - (int)((kk >> 18) & 0x3FFFull);  // pad (kk=0) -> n=0
        float4 bb = boxes_b[n];
        sx[r] = bb.x; sy[r] = bb.y; sz[r] = bb.z; sw[r] = bb.w;
    }
    __syncthreads();

    if (tid >= 64) return;                   // waves 1..3 retire
    const int lane = tid;

    // ---- phase D: sorted walk with distributed alive bitmask ----
    // lane w (<WMAX) owns alive word w: bit b alive iff rank w*64+b < m.
    u64 aliveU = 0ull;
    {
        int base = lane * 64;
        if (base < m) {
            int nb = m - base;
            aliveU = (nb >= 64) ? ~0ull : ((1ull << nb) - 1ull);
        }
    }
    const int W = (m + 63) >> 6;

    int t = 0;
    for (int w = 0; w < W && t < maxo; ++w) {
        u64 cur = __shfl(aliveU, w, 64);
        while (cur != 0ull && t < maxo) {
            const int bit = __builtin_ctzll(cur);
            const int r   = w * 64 + bit;
            const u64 kr  = skey[r];                       // uniform -> broadcast
            const int n   = NMS_N - 1 - (int)((kr >> 18) & 0x3FFFull);
            if (lane == 0) {
                if (OUT64) {
                    out64[t * 3 + 0] = (long long)b;
                    out64[t * 3 + 1] = (long long)c;
                    out64[t * 3 + 2] = (long long)n;
                } else {
                    out32[t * 3 + 0] = b;
                    out32[t * 3 + 1] = c;
                    out32[t * 3 + 2] = n;
                }
            }
            const float4 A = make_float4(sx[r], sy[r], sz[r], sw[r]);
            const float areaA = __fmul_rn(__fsub_rn(A.z, A.x), __fsub_rn(A.w, A.y));
            if (lane == w) aliveU &= ~(1ull << bit);       // self-kill (zero-area safe)
            // live suppression row: ballot of exact IoU per 64-rank word
            for (int w2 = w; w2 < W; ++w2) {
                const int j = w2 * 64 + lane;
                float4 Bj = make_float4(sx[j], sy[j], sz[j], sw[j]);
                bool sup = (j < m) & (iou_exact(A, areaA, Bj) > iou_thr);
                u64 msk = __ballot(sup);
                if (lane == w2) aliveU &= ~msk;
            }
            cur = __shfl(aliveU, w, 64);
            const u64 himask = (bit == 63) ? 0ull : (~0ull << (bit + 1));
            cur &= himask;
            ++t;
        }
    }
    if (lane == 0) flags[bc] = (t < maxo && rem > 0) ? 1 : 0;
}

// ---- slow exact fallback (verified round-2 structure, flag-gated) ----
__device__ __forceinline__ int bucketf(float s) {
    int v = (int)__float_as_uint(s) - 0x3F000000;
    v >>= 15;
    return v < 0 ? 0 : (v > 255 ? 255 : v);
}

template <bool OUT64>
__global__ __launch_bounds__(NTHREADS) void nms_slow(
    const float* __restrict__ boxes,
    const float* __restrict__ scores,
    const int* __restrict__ p_maxout,
    const float* __restrict__ p_iou,
    const float* __restrict__ p_sthr,
    void* __restrict__ out_raw,
    const int* __restrict__ flags)
{
    __shared__ int    hist[NBUCK];
    __shared__ u64    key[SCAP];
    __shared__ float4 cbox[SCAP];
    __shared__ float4 selbox[NMS_MAX_OUT];
    __shared__ u64    s_wmax[NTHREADS / 64];
    __shared__ u64    s_best;
    __shared__ int    s_cnt, s_cutLo, s_cutHi, s_rem, s_state;

    const int tid = threadIdx.x;
    const int bc  = blockIdx.x;
    if (flags && flags[bc] == 0) return;     // uniform exit before any barrier
    const int b   = bc / NMS_C;
    const int c   = bc % NMS_C;

    const float score_thr = p_sthr[0];
    const float iou_thr   = p_iou[0];
    int maxo = p_maxout[0];
    if (maxo > NMS_MAX_OUT) maxo = NMS_MAX_OUT;
    if (maxo < 0) maxo = 0;

    int*       out32 = (int*)out_raw       + (size_t)bc * NMS_MAX_OUT * 3;
    long long* out64 = (long long*)out_raw + (size_t)bc * NMS_MAX_OUT * 3;
    for (int i = tid; i < NMS_MAX_OUT * 3; i += NTHREADS) {
        if (OUT64) out64[i] = -1LL; else out32[i] = -1;
    }

    const float*  sc      = scores + ((size_t)b * NMS_C + c) * NMS_N;
    const float4* sc4     = (const float4*)sc;
    const float4* boxes_b = (const float4*)(boxes + (size_t)b * NMS_N * 4);

    for (int i = tid; i < NBUCK; i += NTHREADS) hist[i] = 0;
    if (tid == 0) s_cnt = 0;
    __syncthreads();
    for (int i = tid; i < NMS_N / 4; i += NTHREADS) {
        float4 s4 = sc4[i];
        float ss[4] = {s4.x, s4.y, s4.z, s4.w};
        #pragma unroll
        for (int j = 0; j < 4; ++j)
            if (ss[j] > score_thr) atomicAdd(&hist[bucketf(ss[j])], 1);
    }
    __syncthreads();

    if (tid == 0) {
        int cum = 0, cut = NBUCK;
        for (int bk = NBUCK - 1; bk >= 0; --bk) {
            int h = hist[bk];
            if (cum > 0 && cum + h > SCAP) break;
            cum += h; cut = bk;
            if (cum >= T_MIN) break;
        }
        s_cutLo = cut; s_cutHi = NBUCK - 1;
        int rem = 0;
        for (int bk = 0; bk < cut; ++bk) rem += hist[bk];
        s_rem = rem;
    }
    __syncthreads();

    auto compact = [&](int lo, int hi) {
        for (int i = tid; i < NMS_N / 4; i += NTHREADS) {
            float4 s4 = sc4[i];
            float ss[4] = {s4.x, s4.y, s4.z, s4.w};
            #pragma unroll
            for (int j = 0; j < 4; ++j) {
                float s = ss[j];
                if (s > score_thr) {
                    int bk = bucketf(s);
                    if (bk >= lo && bk <= hi) {
                        int n = i * 4 + j;
                        int p = atomicAdd(&s_cnt, 1);
                        if (p < SCAP) {
                            key[p] = ((u64)__float_as_uint(s) << 24)
                                   | ((u64)(NMS_N - 1 - n) << 10)
                                   | (u64)p;
                            cbox[p] = boxes_b[n];
                        }
                    }
                }
            }
        }
    };
    compact(s_cutLo, s_cutHi);
    __syncthreads();

    int t = 0;
    while (t < maxo) {
        int m = s_cnt; if (m > SCAP) m = SCAP;
        u64 lmax = 0ull;
        for (int i = tid; i < m; i += NTHREADS) {
            u64 k = key[i];
            if (k > lmax) lmax = k;
        }
        #pragma unroll
        for (int off = 32; off > 0; off >>= 1) {
            u64 o = __shfl_down(lmax, off);
            if (o > lmax) lmax = o;
        }
        if ((tid & 63) == 0) s_wmax[tid >> 6] = lmax;
        __syncthreads();
        if (tid == 0) {
            u64 best = s_wmax[0];
            #pragma unroll
            for (int w = 1; w < NTHREADS / 64; ++w)
                if (s_wmax[w] > best) best = s_wmax[w];
            s_best = best;
            if (best) {
                int slot = (int)(best & 0x3FFull);
                int n    = NMS_N - 1 - (int)((best >> 10) & 0x3FFFull);
                key[slot] = 0ull;
                if (OUT64) {
                    out64[t * 3 + 0] = (long long)b;
                    out64[t * 3 + 1] = (long long)c;
                    out64[t * 3 + 2] = (long long)n;
                } else {
                    out32[t * 3 + 0] = b;
                    out32[t * 3 + 1] = c;
                    out32[t * 3 + 2] = n;
                }
                selbox[t] = cbox[slot];
                s_state = 0;
            } else if (s_rem == 0) {
                s_state = 2;
            } else {
                int hiB = s_cutLo - 1;
                int cum = 0, cut = hiB + 1;
                for (int bk = hiB; bk >= 0; --bk) {
                    int h = hist[bk];
                    if (cum > 0 && cum + h > SCAP) break;
                    cum += h; cut = bk;
                    if (cum >= T_MIN) break;
                }
                s_cutLo = cut; s_cutHi = hiB;
                int rem = 0;
                for (int bk = 0; bk < cut; ++bk) rem += hist[bk];
                s_rem = rem;
                s_cnt = 0;
                s_state = 1;
            }
        }
        __syncthreads();

        if (s_state == 2) break;

        if (s_state == 0) {
            const float4 A = selbox[t];
            const float areaA = __fmul_rn(__fsub_rn(A.z, A.x), __fsub_rn(A.w, A.y));
            int m0 = s_cnt; if (m0 > SCAP) m0 = SCAP;
            for (int i = tid; i < m0; i += NTHREADS) {
                u64 k = key[i];
                if (!k) continue;
                if (iou_exact(A, areaA, cbox[i]) > iou_thr) key[i] = 0ull;
            }
            __syncthreads();
            ++t;
        } else {
            compact(s_cutLo, s_cutHi);
            __syncthreads();
            int m2 = s_cnt; if (m2 > SCAP) m2 = SCAP;
            for (int i = tid; i < m2; i += NTHREADS) {
                u64 k = key[i];
                if (!k) continue;
                float4 Bx = cbox[i];
                for (int j = 0; j < t; ++j) {
                    float4 A = selbox[j];
                    float areaA = __fmul_rn(__fsub_rn(A.z, A.x), __fsub_rn(A.w, A.y));
                    if (iou_exact(A, areaA, Bx) > iou_thr) { key[i] = 0ull; break; }
                }
            }
            __syncthreads();
        }
    }
}

extern "C" void kernel_launch(void* const* d_in, const int* in_sizes, int n_in,
                              void* d_out, int out_size, void* d_ws, size_t ws_size,
                              hipStream_t stream) {
    const float* boxes  = (const float*)d_in[0];
    const float* scores = (const float*)d_in[1];
    const int*   p_maxo = (const int*)d_in[2];
    const float* p_iou  = (const float*)d_in[3];
    const float* p_sthr = (const float*)d_in[4];

    const dim3 grid(NMS_B * NMS_C);
    const dim3 block(NTHREADS);
    const bool out64 = (out_size == NMS_B * NMS_C * NMS_MAX_OUT * 3 * 2);

    int* flags = (ws_size >= (size_t)NMS_B * NMS_C * sizeof(int)) ? (int*)d_ws : nullptr;

    if (out64) {
        if (flags)
            hipLaunchKernelGGL(nms_fast<true>, grid, block, 0, stream,
                               boxes, scores, p_maxo, p_iou, p_sthr, d_out, flags);
        hipLaunchKernelGGL(nms_slow<true>, grid, block, 0, stream,
                           boxes, scores, p_maxo, p_iou, p_sthr, d_out, flags);
    } else {
        if (flags)
            hipLaunchKernelGGL(nms_fast<false>, grid, block, 0, stream,
                               boxes, scores, p_maxo, p_iou, p_sthr, d_out, flags);
        hipLaunchKernelGGL(nms_slow<false>, grid, block, 0, stream,
                           boxes, scores, p_maxo, p_iou, p_sthr, d_out, flags);
    }
}

// Round 6
// 85.328 us; speedup vs baseline: 1.4804x; 1.1271x over previous
//
#include <hip/hip_runtime.h>
#include <stdint.h>

// ONNX NonMaxSuppression: B=8, N=16384, C=80, MAX_OUT=50
// nms_fast, one block per (b,c):
//   phase A: streaming score scan (16-deep load unroll); push keys
//            (score_bits<<32 | invidx<<18) above fixed optimistic cutoff
//   phase B: bitonic sort (desc) of 512-padded keys, 4 waves
//   phase C: gather candidate boxes by rank into LDS SoA
//   phase D: wave-0 sorted walk. Alive bitmask REPLICATED in all lanes
//            (8 u64 regs); column boxes+areas hoisted to registers.
//            Per selection: local ctz -> uniform LDS reads of the selected
//            row -> 8x register IoU + __ballot -> AND into alive words.
//            No __shfl, no LDS traffic in the suppression loop.
// Exactness: overflow or exhaustion-with-remainder flags the lane in d_ws;
// gated nms_slow (verified adaptive 2-pass kernel) re-solves those lanes.

#define NMS_B 8
#define NMS_N 16384
#define NMS_C 80
#define NMS_MAX_OUT 50
#define NTHREADS 256

// fast kernel
#define OPT_THR 0.9765625f   // E[cnt]=384, sigma~19.4; FCAP=512 -> +6.6 sigma
#define FCAP 512
#define WMAX (FCAP / 64)     // 8 alive words

// slow (fallback) kernel
#define NBUCK 256
#define SCAP 1024
#define T_MIN 320

typedef unsigned long long u64;
typedef unsigned int u32;

__device__ __forceinline__ float iou_exact(float4 A, float areaA, float4 Bx) {
    float x1 = fmaxf(A.x, Bx.x);
    float y1 = fmaxf(A.y, Bx.y);
    float x2 = fminf(A.z, Bx.z);
    float y2 = fminf(A.w, Bx.w);
    float dx = fmaxf(__fsub_rn(x2, x1), 0.0f);
    float dy = fmaxf(__fsub_rn(y2, y1), 0.0f);
    if (!(dx > 0.0f && dy > 0.0f)) return 0.0f;   // inter==0 -> iou==0 exactly
    float inter = __fmul_rn(dx, dy);
    float areaB = __fmul_rn(__fsub_rn(Bx.z, Bx.x), __fsub_rn(Bx.w, Bx.y));
    float uni   = __fsub_rn(__fadd_rn(areaA, areaB), inter);
    return __fdiv_rn(inter, fmaxf(uni, 1e-9f));
}

// same chain, areaB precomputed (value-identical: areaB = (x2-x1)*(y2-y1))
__device__ __forceinline__ float iou_pre(float4 A, float areaA, float4 Bx, float areaB) {
    float x1 = fmaxf(A.x, Bx.x);
    float y1 = fmaxf(A.y, Bx.y);
    float x2 = fminf(A.z, Bx.z);
    float y2 = fminf(A.w, Bx.w);
    float dx = fmaxf(__fsub_rn(x2, x1), 0.0f);
    float dy = fmaxf(__fsub_rn(y2, y1), 0.0f);
    if (!(dx > 0.0f && dy > 0.0f)) return 0.0f;
    float inter = __fmul_rn(dx, dy);
    float uni   = __fsub_rn(__fadd_rn(areaA, areaB), inter);
    return __fdiv_rn(inter, fmaxf(uni, 1e-9f));
}

template <bool OUT64>
__global__ __launch_bounds__(NTHREADS) void nms_fast(
    const float* __restrict__ boxes,
    const float* __restrict__ scores,
    const int* __restrict__ p_maxout,
    const float* __restrict__ p_iou,
    const float* __restrict__ p_sthr,
    void* __restrict__ out_raw,
    int* __restrict__ flags)
{
    __shared__ u64   skey[FCAP];
    __shared__ float sx[FCAP], sy[FCAP], sz[FCAP], sw[FCAP];
    __shared__ int   s_cnt, s_total;

    const int tid = threadIdx.x;
    const int bc  = blockIdx.x;
    const int b   = bc / NMS_C;
    const int c   = bc % NMS_C;

    const float score_thr = p_sthr[0];
    const float iou_thr   = p_iou[0];
    int maxo = p_maxout[0];
    if (maxo > NMS_MAX_OUT) maxo = NMS_MAX_OUT;
    if (maxo < 0) maxo = 0;

    int*       out32 = (int*)out_raw       + (size_t)bc * NMS_MAX_OUT * 3;
    long long* out64 = (long long*)out_raw + (size_t)bc * NMS_MAX_OUT * 3;
    for (int i = tid; i < NMS_MAX_OUT * 3; i += NTHREADS) {
        if (OUT64) out64[i] = -1LL; else out32[i] = -1;
    }

    // pad keys, init counters
    skey[tid] = 0ull;
    skey[tid + 256] = 0ull;
    if (tid == 0) { s_cnt = 0; s_total = 0; }
    __syncthreads();

    const float4* sc4     = (const float4*)(scores + ((size_t)b * NMS_C + c) * NMS_N);
    const float4* boxes_b = (const float4*)(boxes + (size_t)b * NMS_N * 4);

    // ---- phase A: streaming score scan, all 16 loads in flight ----
    float4 av[16];
    #pragma unroll
    for (int u = 0; u < 16; ++u) av[u] = sc4[u * NTHREADS + tid];

    int local_total = 0;
    #pragma unroll
    for (int u = 0; u < 16; ++u) {
        const int i = u * NTHREADS + tid;
        float ss[4] = {av[u].x, av[u].y, av[u].z, av[u].w};
        #pragma unroll
        for (int j = 0; j < 4; ++j) {
            float s = ss[j];
            bool cand = (s > score_thr);
            local_total += cand ? 1 : 0;
            if (cand && s >= OPT_THR) {          // rare (~2.3%)
                int n = i * 4 + j;
                int p = atomicAdd(&s_cnt, 1);
                if (p < FCAP) {
                    skey[p] = ((u64)__float_as_uint(s) << 32)
                            | ((u64)(NMS_N - 1 - n) << 18);
                }
            }
        }
    }
    atomicAdd(&s_total, local_total);
    __syncthreads();

    const int  m        = (s_cnt < FCAP) ? s_cnt : FCAP;
    const bool overflow = (s_cnt > FCAP);
    const int  rem      = s_total - s_cnt;   // candidates below optimistic cut

    if (overflow) {                          // uniform block-wide bail
        if (tid == 0) flags[bc] = 1;
        return;
    }

    // ---- phase B: bitonic sort descending over FCAP=512 keys ----
    for (int kk = 2; kk <= FCAP; kk <<= 1) {
        for (int jj = kk >> 1; jj > 0; jj >>= 1) {
            int i  = 2 * jj * (tid / jj) + (tid % jj);
            int p2 = i + jj;
            bool dirDesc = ((i & kk) == 0);
            u64 a = skey[i], bkey = skey[p2];
            bool swap = dirDesc ? (a < bkey) : (a > bkey);
            if (swap) { skey[i] = bkey; skey[p2] = a; }
            __syncthreads();
        }
    }

    // ---- phase C: gather boxes by rank into SoA LDS ----
    #pragma unroll
    for (int r = tid; r < FCAP; r += NTHREADS) {
        u64 kk = skey[r];
        int n = NMS_N - 1 - (int)((kk >> 18) & 0x3FFFull);  // pad (kk=0) -> n=0
        float4 bb = boxes_b[n];
        sx[r] = bb.x; sy[r] = bb.y; sz[r] = bb.z; sw[r] = bb.w;
    }
    __syncthreads();

    if (tid >= 64) return;                   // waves 1..3 retire
    const int lane = tid;

    // ---- phase D: sorted walk, alive mask replicated in every lane ----
    // hoist this lane's column boxes + areas into registers (static idx)
    float4 bxc[WMAX];
    float  areaBc[WMAX];
    #pragma unroll
    for (int w2 = 0; w2 < WMAX; ++w2) {
        const int j = w2 * 64 + lane;
        bxc[w2] = make_float4(sx[j], sy[j], sz[j], sw[j]);
        areaBc[w2] = __fmul_rn(__fsub_rn(bxc[w2].z, bxc[w2].x),
                               __fsub_rn(bxc[w2].w, bxc[w2].y));
    }

    u64 aliveW[WMAX];
    #pragma unroll
    for (int w2 = 0; w2 < WMAX; ++w2) {
        const int base = w2 * 64;
        aliveW[w2] = (m > base)
                   ? ((m - base >= 64) ? ~0ull : ((1ull << (m - base)) - 1ull))
                   : 0ull;
    }

    int need_slow = 0;
    for (int t = 0; t < maxo; ++t) {
        // lane-local find of lowest-rank alive candidate (no shfl)
        int w = WMAX; u64 cw = 0ull;
        #pragma unroll
        for (int q = WMAX - 1; q >= 0; --q)
            if (aliveW[q] != 0ull) { w = q; cw = aliveW[q]; }
        if (w == WMAX) {                     // exhausted
            if (rem > 0) need_slow = 1;
            break;
        }
        const int bit = __builtin_ctzll(cw);
        const int r   = w * 64 + bit;

        const u64 kr = skey[r];              // uniform -> broadcast
        const int n  = NMS_N - 1 - (int)((kr >> 18) & 0x3FFFull);
        if (lane == 0) {
            if (OUT64) {
                out64[t * 3 + 0] = (long long)b;
                out64[t * 3 + 1] = (long long)c;
                out64[t * 3 + 2] = (long long)n;
            } else {
                out32[t * 3 + 0] = b;
                out32[t * 3 + 1] = c;
                out32[t * 3 + 2] = n;
            }
        }
        const float4 A = make_float4(sx[r], sy[r], sz[r], sw[r]);  // uniform
        const float areaA = __fmul_rn(__fsub_rn(A.z, A.x), __fsub_rn(A.w, A.y));

        // suppression row: register IoU + ballot per word; self-kill folded in
        #pragma unroll
        for (int w2 = 0; w2 < WMAX; ++w2) {
            const bool valid = (w2 * 64 + lane) < m;
            const bool sup = valid &&
                (iou_pre(A, areaA, bxc[w2], areaBc[w2]) > iou_thr);
            u64 kill = __ballot(sup);
            if (w2 == w) kill |= (1ull << bit);   // self (zero-area safe)
            aliveW[w2] &= ~kill;
        }
    }
    if (lane == 0) flags[bc] = need_slow;
}

// ---- slow exact fallback (verified round-2 structure, flag-gated) ----
__device__ __forceinline__ int bucketf(float s) {
    int v = (int)__float_as_uint(s) - 0x3F000000;
    v >>= 15;
    return v < 0 ? 0 : (v > 255 ? 255 : v);
}

template <bool OUT64>
__global__ __launch_bounds__(NTHREADS) void nms_slow(
    const float* __restrict__ boxes,
    const float* __restrict__ scores,
    const int* __restrict__ p_maxout,
    const float* __restrict__ p_iou,
    const float* __restrict__ p_sthr,
    void* __restrict__ out_raw,
    const int* __restrict__ flags)
{
    __shared__ int    hist[NBUCK];
    __shared__ u64    key[SCAP];
    __shared__ float4 cbox[SCAP];
    __shared__ float4 selbox[NMS_MAX_OUT];
    __shared__ u64    s_wmax[NTHREADS / 64];
    __shared__ u64    s_best;
    __shared__ int    s_cnt, s_cutLo, s_cutHi, s_rem, s_state;

    const int tid = threadIdx.x;
    const int bc  = blockIdx.x;
    if (flags && flags[bc] == 0) return;     // uniform exit before any barrier
    const int b   = bc / NMS_C;
    const int c   = bc % NMS_C;

    const float score_thr = p_sthr[0];
    const float iou_thr   = p_iou[0];
    int maxo = p_maxout[0];
    if (maxo > NMS_MAX_OUT) maxo = NMS_MAX_OUT;
    if (maxo < 0) maxo = 0;

    int*       out32 = (int*)out_raw       + (size_t)bc * NMS_MAX_OUT * 3;
    long long* out64 = (long long*)out_raw + (size_t)bc * NMS_MAX_OUT * 3;
    for (int i = tid; i < NMS_MAX_OUT * 3; i += NTHREADS) {
        if (OUT64) out64[i] = -1LL; else out32[i] = -1;
    }

    const float*  sc      = scores + ((size_t)b * NMS_C + c) * NMS_N;
    const float4* sc4     = (const float4*)sc;
    const float4* boxes_b = (const float4*)(boxes + (size_t)b * NMS_N * 4);

    for (int i = tid; i < NBUCK; i += NTHREADS) hist[i] = 0;
    if (tid == 0) s_cnt = 0;
    __syncthreads();
    for (int i = tid; i < NMS_N / 4; i += NTHREADS) {
        float4 s4 = sc4[i];
        float ss[4] = {s4.x, s4.y, s4.z, s4.w};
        #pragma unroll
        for (int j = 0; j < 4; ++j)
            if (ss[j] > score_thr) atomicAdd(&hist[bucketf(ss[j])], 1);
    }
    __syncthreads();

    if (tid == 0) {
        int cum = 0, cut = NBUCK;
        for (int bk = NBUCK - 1; bk >= 0; --bk) {
            int h = hist[bk];
            if (cum > 0 && cum + h > SCAP) break;
            cum += h; cut = bk;
            if (cum >= T_MIN) break;
        }
        s_cutLo = cut; s_cutHi = NBUCK - 1;
        int rem = 0;
        for (int bk = 0; bk < cut; ++bk) rem += hist[bk];
        s_rem = rem;
    }
    __syncthreads();

    auto compact = [&](int lo, int hi) {
        for (int i = tid; i < NMS_N / 4; i += NTHREADS) {
            float4 s4 = sc4[i];
            float ss[4] = {s4.x, s4.y, s4.z, s4.w};
            #pragma unroll
            for (int j = 0; j < 4; ++j) {
                float s = ss[j];
                if (s > score_thr) {
                    int bk = bucketf(s);
                    if (bk >= lo && bk <= hi) {
                        int n = i * 4 + j;
                        int p = atomicAdd(&s_cnt, 1);
                        if (p < SCAP) {
                            key[p] = ((u64)__float_as_uint(s) << 24)
                                   | ((u64)(NMS_N - 1 - n) << 10)
                                   | (u64)p;
                            cbox[p] = boxes_b[n];
                        }
                    }
                }
            }
        }
    };
    compact(s_cutLo, s_cutHi);
    __syncthreads();

    int t = 0;
    while (t < maxo) {
        int m = s_cnt; if (m > SCAP) m = SCAP;
        u64 lmax = 0ull;
        for (int i = tid; i < m; i += NTHREADS) {
            u64 k = key[i];
            if (k > lmax) lmax = k;
        }
        #pragma unroll
        for (int off = 32; off > 0; off >>= 1) {
            u64 o = __shfl_down(lmax, off);
            if (o > lmax) lmax = o;
        }
        if ((tid & 63) == 0) s_wmax[tid >> 6] = lmax;
        __syncthreads();
        if (tid == 0) {
            u64 best = s_wmax[0];
            #pragma unroll
            for (int w = 1; w < NTHREADS / 64; ++w)
                if (s_wmax[w] > best) best = s_wmax[w];
            s_best = best;
            if (best) {
                int slot = (int)(best & 0x3FFull);
                int n    = NMS_N - 1 - (int)((best >> 10) & 0x3FFFull);
                key[slot] = 0ull;
                if (OUT64) {
                    out64[t * 3 + 0] = (long long)b;
                    out64[t * 3 + 1] = (long long)c;
                    out64[t * 3 + 2] = (long long)n;
                } else {
                    out32[t * 3 + 0] = b;
                    out32[t * 3 + 1] = c;
                    out32[t * 3 + 2] = n;
                }
                selbox[t] = cbox[slot];
                s_state = 0;
            } else if (s_rem == 0) {
                s_state = 2;
            } else {
                int hiB = s_cutLo - 1;
                int cum = 0, cut = hiB + 1;
                for (int bk = hiB; bk >= 0; --bk) {
                    int h = hist[bk];
                    if (cum > 0 && cum + h > SCAP) break;
                    cum += h; cut = bk;
                    if (cum >= T_MIN) break;
                }
                s_cutLo = cut; s_cutHi = hiB;
                int rem = 0;
                for (int bk = 0; bk < cut; ++bk) rem += hist[bk];
                s_rem = rem;
                s_cnt = 0;
                s_state = 1;
            }
        }
        __syncthreads();

        if (s_state == 2) break;

        if (s_state == 0) {
            const float4 A = selbox[t];
            const float areaA = __fmul_rn(__fsub_rn(A.z, A.x), __fsub_rn(A.w, A.y));
            int m0 = s_cnt; if (m0 > SCAP) m0 = SCAP;
            for (int i = tid; i < m0; i += NTHREADS) {
                u64 k = key[i];
                if (!k) continue;
                if (iou_exact(A, areaA, cbox[i]) > iou_thr) key[i] = 0ull;
            }
            __syncthreads();
            ++t;
        } else {
            compact(s_cutLo, s_cutHi);
            __syncthreads();
            int m2 = s_cnt; if (m2 > SCAP) m2 = SCAP;
            for (int i = tid; i < m2; i += NTHREADS) {
                u64 k = key[i];
                if (!k) continue;
                float4 Bx = cbox[i];
                for (int j = 0; j < t; ++j) {
                    float4 A = selbox[j];
                    float areaA = __fmul_rn(__fsub_rn(A.z, A.x), __fsub_rn(A.w, A.y));
                    if (iou_exact(A, areaA, Bx) > iou_thr) { key[i] = 0ull; break; }
                }
            }
            __syncthreads();
        }
    }
}

extern "C" void kernel_launch(void* const* d_in, const int* in_sizes, int n_in,
                              void* d_out, int out_size, void* d_ws, size_t ws_size,
                              hipStream_t stream) {
    const float* boxes  = (const float*)d_in[0];
    const float* scores = (const float*)d_in[1];
    const int*   p_maxo = (const int*)d_in[2];
    const float* p_iou  = (const float*)d_in[3];
    const float* p_sthr = (const float*)d_in[4];

    const dim3 grid(NMS_B * NMS_C);
    const dim3 block(NTHREADS);
    const bool out64 = (out_size == NMS_B * NMS_C * NMS_MAX_OUT * 3 * 2);

    int* flags = (ws_size >= (size_t)NMS_B * NMS_C * sizeof(int)) ? (int*)d_ws : nullptr;

    if (out64) {
        if (flags)
            hipLaunchKernelGGL(nms_fast<true>, grid, block, 0, stream,
                               boxes, scores, p_maxo, p_iou, p_sthr, d_out, flags);
        hipLaunchKernelGGL(nms_slow<true>, grid, block, 0, stream,
                           boxes, scores, p_maxo, p_iou, p_sthr, d_out, flags);
    } else {
        if (flags)
            hipLaunchKernelGGL(nms_fast<false>, grid, block, 0, stream,
                               boxes, scores, p_maxo, p_iou, p_sthr, d_out, flags);
        hipLaunchKernelGGL(nms_slow<false>, grid, block, 0, stream,
                           boxes, scores, p_maxo, p_iou, p_sthr, d_out, flags);
    }
}